// Round 19
// baseline (129.239 us; speedup 1.0000x reference)
//
#include <hip/hip_runtime.h>

#define N_NODES 50000
#define E_EDGES 1600000
#define HC 128
#define NEG_SLOPE 0.2f
#define SM_EPS 1e-16f
#define NBKT 782          // ceil(50000/64) coarse buckets (dst>>6)
#define BKT_STRIDE 2600   // slack per bucket (avg 2046, +12 sigma)
#define EPB1 4096         // edges per hist-role block
#define NB_GEMM 782
#define NB_HIST 391

typedef __attribute__((ext_vector_type(8))) short short8v;
typedef __attribute__((ext_vector_type(4))) float f32x4;

union U8 { uint4 u; short8v s; };

__device__ inline unsigned bf16pack(float a, float b) {
  unsigned ua = __float_as_uint(a), ub = __float_as_uint(b);
  ua = (ua + 0x7fffu + ((ua >> 16) & 1u)) >> 16;
  ub = (ub + 0x7fffu + ((ub >> 16) & 1u)) >> 16;
  return ua | (ub << 16);
}

// ---------------- K0: build wT[144][256] bf16 (W^T with wvec cols); init gcursor --
__global__ __launch_bounds__(256) void k0_init(
    const float* __restrict__ v_mapping,  // [64,256]
    const float* __restrict__ att_src,    // [64]
    const float* __restrict__ att_dst,    // [64]
    const float* __restrict__ W,          // [256,128]
    unsigned short* __restrict__ wT,      // [144,256] bf16
    int* __restrict__ gcursor) {
  const int tid = threadIdx.x, bid = blockIdx.x;
  if (bid < 4) {
    const int i = bid * 256 + tid;
    if (i < NBKT) gcursor[i] = i * BKT_STRIDE;
  }

  __shared__ float wv[2][256];
  {
    const int j = tid;
    float ns = 0.f, nd = 0.f;
    for (int f = 0; f < 64; ++f) {
      float a = att_src[f]; ns = fmaf(a, a, ns);
      float b = att_dst[f]; nd = fmaf(b, b, nd);
    }
    ns = fmaxf(sqrtf(ns), 1e-12f);
    nd = fmaxf(sqrtf(nd), 1e-12f);
    float s = 0.f, d = 0.f;
    for (int f = 0; f < 64; ++f) {
      float v = v_mapping[f * 256 + j];
      s = fmaf(v, att_src[f], s);
      d = fmaf(v, att_dst[f], d);
    }
    wv[0][j] = s / ns;
    wv[1][j] = d / nd;
  }
  __syncthreads();

#pragma unroll
  for (int r = 0; r < 8; ++r) {
    const int n = bid * 8 + r;
    const int k = tid;
    float v;
    if (n < 128) v = W[k * 128 + n];
    else if (n == 128) v = wv[0][k];
    else if (n == 129) v = wv[1][k];
    else v = 0.f;
    unsigned u = __float_as_uint(v);
    u = (u + 0x7fffu + ((u >> 16) & 1u)) >> 16;
    wT[n * 256 + k] = (unsigned short)u;
  }
}

// ---------------- K1F: role-fused — 2:1 interleave of GEMM (reg-A) and hist -------
__global__ __launch_bounds__(256) void k1_fused(
    const float* __restrict__ x,            // [N,256]
    const unsigned short* __restrict__ wT,  // [144,256] bf16
    unsigned* __restrict__ xpb,             // [N,64] bf16x2 packed
    float* __restrict__ a_src, float* __restrict__ a_dst,
    const int* __restrict__ ei,
    int* __restrict__ gcursor, unsigned* __restrict__ coarse) {
  __shared__ char smem[17408];
  const int bid = blockIdx.x;
  const int tid = threadIdx.x;
  const int r3 = bid % 3, q3 = bid / 3;

  if (r3 == 2) {
    // -------- bucket-scatter role: 4096 edges; rank from FIRST hist pass
    const int hid = q3;
    if (hid >= NB_HIST) return;
    int* chist = (int*)smem;
    int* gbase = (int*)(smem + 3200);
    const int ebase = hid * EPB1;
    for (int b = tid; b < NBKT; b += 256) chist[b] = 0;
    __syncthreads();

    // pass A: histogram; the atomic return IS the within-block rank
    int rnk[16];
#pragma unroll
    for (int i = 0; i < 16; ++i) {
      const int e = ebase + i * 256 + tid;
      rnk[i] = (e < E_EDGES) ? atomicAdd(&chist[ei[E_EDGES + e] >> 6], 1) : 0;
    }
    __syncthreads();

    // claim one global range per nonempty bucket
    for (int b = tid; b < NBKT; b += 256) {
      const int c = chist[b];
      if (c > 0) gbase[b] = atomicAdd(&gcursor[b], c);
    }
    __syncthreads();

    // pass B: pure scatter (reload s,d from L2; no cursor atomics)
#pragma unroll
    for (int i = 0; i < 16; ++i) {
      const int e = ebase + i * 256 + tid;
      if (e < E_EDGES) {
        const int s = ei[e];
        const int d = ei[E_EDGES + e];
        const int b = d >> 6;
        const int pos = gbase[b] + rnk[i];
        if (pos < (b + 1) * BKT_STRIDE)
          coarse[pos] = (unsigned)s | ((unsigned)(d & 63) << 16);
      }
    }
    return;
  }

  // -------- GEMM role: A-frags from global into registers, 2-chunk epilogue
  const int gid = q3 * 2 + r3;
  if (gid >= NB_GEMM) return;
  const int w = tid >> 6, lane = tid & 63;
  const int rowbase = gid * 64;
  const int m = lane & 15, kq = lane >> 4;

  const int arow_idx = rowbase + w * 16 + m;
  const int arow_c = arow_idx < N_NODES ? arow_idx : N_NODES - 1;
  const float4* xr = (const float4*)(x + (size_t)arow_c * 256);
  short8v af[8];
#pragma unroll
  for (int ks = 0; ks < 8; ++ks) {
    const float4 p0 = xr[kq * 2 + ks * 8];
    const float4 p1 = xr[kq * 2 + ks * 8 + 1];
    U8 t;
    t.u = make_uint4(bf16pack(p0.x, p0.y), bf16pack(p0.z, p0.w),
                     bf16pack(p1.x, p1.y), bf16pack(p1.z, p1.w));
    af[ks] = t.s;
  }

  f32x4 acc[9];
#pragma unroll
  for (int t = 0; t < 9; ++t) acc[t] = (f32x4){0.f, 0.f, 0.f, 0.f};

#pragma unroll
  for (int ks = 0; ks < 8; ++ks) {
#pragma unroll
    for (int ct = 0; ct < 9; ++ct) {
      const short8v bf = *(const short8v*)(wT + (ct * 16 + m) * 256 + ks * 32 + kq * 8);
      acc[ct] = __builtin_amdgcn_mfma_f32_16x16x32_bf16(af[ks], bf, acc[ct], 0, 0, 0);
    }
  }

  if (m < 2) {
    float* ap = m ? a_dst : a_src;
#pragma unroll
    for (int i = 0; i < 4; ++i) {
      const int rg = rowbase + w * 16 + kq * 4 + i;
      if (rg < N_NODES) ap[rg] = acc[8][i];
    }
  }

  float* cs = (float*)smem + w * 1088;
  const int prow = lane & 15, q = lane >> 4;
  const int growp = rowbase + w * 16 + prow;
#pragma unroll
  for (int half = 0; half < 2; ++half) {
#pragma unroll
    for (int ct = 0; ct < 4; ++ct)
#pragma unroll
      for (int i = 0; i < 4; ++i)
        cs[(kq * 4 + i) * 68 + ct * 16 + m] = acc[half * 4 + ct][i];
    __syncthreads();
    unsigned uu[8];
#pragma unroll
    for (int u2 = 0; u2 < 8; ++u2) {
      const float2 f2 = *(const float2*)&cs[prow * 68 + q * 16 + u2 * 2];
      uu[u2] = bf16pack(f2.x, f2.y);
    }
    if (growp < N_NODES) {
      uint4* d4 = (uint4*)&xpb[(size_t)growp * 64 + half * 32 + q * 8];
      d4[0] = make_uint4(uu[0], uu[1], uu[2], uu[3]);
      d4[1] = make_uint4(uu[4], uu[5], uu[6], uu[7]);
    }
    __syncthreads();
  }
}

// ---------------- KC2: ev + per-bucket LDS counting-sort + gather-reduce, 512 thr -
__global__ __launch_bounds__(512) void kc2_reduce(
    const int* __restrict__ gcursor, const unsigned* __restrict__ coarse,
    const float* __restrict__ a_src, const float* __restrict__ a_dst,
    const unsigned* __restrict__ xpb,   // [N,64] bf16x2
    const float* __restrict__ bias,     // [128]
    float* __restrict__ out) {
  __shared__ unsigned sorted[BKT_STRIDE];  // {src:16 | ev_bf16:16}
  __shared__ int hist[64], cur[64];
  __shared__ int base[65];
  __shared__ float adl[64];
  const int b = blockIdx.x;
  const int tid = threadIdx.x;
  const int cstart = b * BKT_STRIDE;
  const int cnt = min(gcursor[b] - cstart, BKT_STRIDE);

  if (tid < 64) {
    hist[tid] = 0; cur[tid] = 0;
    const int dg = (b << 6) | tid;
    adl[tid] = (dg < N_NODES) ? a_dst[dg] : 0.f;
  }
  __syncthreads();

  for (int j = tid; j < cnt; j += 512)
    atomicAdd(&hist[(coarse[cstart + j] >> 16) & 63], 1);
  __syncthreads();

  if (tid < 64) {
    const int h = hist[tid];
    int inc = h;
#pragma unroll
    for (int off = 1; off < 64; off <<= 1) {
      int t = __shfl_up(inc, off);
      if (tid >= off) inc += t;
    }
    base[tid] = inc - h;
    if (tid == 63) base[64] = inc;
  }
  __syncthreads();

  for (int j = tid; j < cnt; j += 512) {
    const unsigned e2 = coarse[cstart + j];
    const int src = e2 & 0xffffu;
    const int dloc = (e2 >> 16) & 63;
    float a = a_src[src] + adl[dloc];
    a = a > 0.f ? a : NEG_SLOPE * a;
    unsigned uev = __float_as_uint(__expf(a));
    uev = (uev + 0x7fffu + ((uev >> 16) & 1u)) >> 16;
    const int p = base[dloc] + atomicAdd(&cur[dloc], 1);
    sorted[p] = (unsigned)src | (uev << 16);
  }
  __syncthreads();

  const int g = tid >> 4, gl = tid & 15;
  const uint4* xp4 = (const uint4*)xpb;
  const float4* br = (const float4*)bias;
  const float4 b0 = br[2 * gl], b1 = br[2 * gl + 1];

  for (int dl = g; dl < 64; dl += 32) {
    const int dst = (b << 6) | dl;
    if (dst >= N_NODES) break;
    const int s0 = base[dl];
    const int cntd = base[dl + 1] - s0;

    float acc[8];
#pragma unroll
    for (int i = 0; i < 8; ++i) acc[i] = 0.f;
    float den = 0.f;

    int j = 0;
    for (; j + 4 <= cntd; j += 4) {
      unsigned u[4];
      float ev[4];
      uint4 v[4];
#pragma unroll
      for (int t = 0; t < 4; ++t) {
        u[t] = sorted[s0 + j + t];
        ev[t] = __uint_as_float(u[t] & 0xffff0000u);
        v[t] = xp4[(size_t)(u[t] & 0xffffu) * 16 + gl];
      }
#pragma unroll
      for (int t = 0; t < 4; ++t) {
        den += ev[t];
        acc[0] = fmaf(ev[t], __uint_as_float(v[t].x << 16), acc[0]);
        acc[1] = fmaf(ev[t], __uint_as_float(v[t].x & 0xffff0000u), acc[1]);
        acc[2] = fmaf(ev[t], __uint_as_float(v[t].y << 16), acc[2]);
        acc[3] = fmaf(ev[t], __uint_as_float(v[t].y & 0xffff0000u), acc[3]);
        acc[4] = fmaf(ev[t], __uint_as_float(v[t].z << 16), acc[4]);
        acc[5] = fmaf(ev[t], __uint_as_float(v[t].z & 0xffff0000u), acc[5]);
        acc[6] = fmaf(ev[t], __uint_as_float(v[t].w << 16), acc[6]);
        acc[7] = fmaf(ev[t], __uint_as_float(v[t].w & 0xffff0000u), acc[7]);
      }
    }
    for (; j < cntd; ++j) {
      const unsigned u = sorted[s0 + j];
      const float ev = __uint_as_float(u & 0xffff0000u);
      const uint4 v = xp4[(size_t)(u & 0xffffu) * 16 + gl];
      den += ev;
      acc[0] = fmaf(ev, __uint_as_float(v.x << 16), acc[0]);
      acc[1] = fmaf(ev, __uint_as_float(v.x & 0xffff0000u), acc[1]);
      acc[2] = fmaf(ev, __uint_as_float(v.y << 16), acc[2]);
      acc[3] = fmaf(ev, __uint_as_float(v.y & 0xffff0000u), acc[3]);
      acc[4] = fmaf(ev, __uint_as_float(v.z << 16), acc[4]);
      acc[5] = fmaf(ev, __uint_as_float(v.z & 0xffff0000u), acc[5]);
      acc[6] = fmaf(ev, __uint_as_float(v.w << 16), acc[6]);
      acc[7] = fmaf(ev, __uint_as_float(v.w & 0xffff0000u), acc[7]);
    }

    const float inv = 1.f / (den + SM_EPS);
    const uint4 ur = xp4[(size_t)dst * 16 + gl];
    float4 o0, o1;
    o0.x = __uint_as_float(ur.x << 16)         + b0.x + acc[0] * inv;
    o0.y = __uint_as_float(ur.x & 0xffff0000u) + b0.y + acc[1] * inv;
    o0.z = __uint_as_float(ur.y << 16)         + b0.z + acc[2] * inv;
    o0.w = __uint_as_float(ur.y & 0xffff0000u) + b0.w + acc[3] * inv;
    o1.x = __uint_as_float(ur.z << 16)         + b1.x + acc[4] * inv;
    o1.y = __uint_as_float(ur.z & 0xffff0000u) + b1.y + acc[5] * inv;
    o1.z = __uint_as_float(ur.w << 16)         + b1.z + acc[6] * inv;
    o1.w = __uint_as_float(ur.w & 0xffff0000u) + b1.w + acc[7] * inv;
    float4* orow = (float4*)(out + (size_t)dst * HC);
    orow[2 * gl] = o0;
    orow[2 * gl + 1] = o1;
  }
}

extern "C" void kernel_launch(void* const* d_in, const int* in_sizes, int n_in,
                              void* d_out, int out_size, void* d_ws, size_t ws_size,
                              hipStream_t stream) {
  const float* x         = (const float*)d_in[0];
  const int*   ei        = (const int*)d_in[1];
  const float* v_mapping = (const float*)d_in[2];
  const float* W_src     = (const float*)d_in[3];
  const float* att_src   = (const float*)d_in[4];
  const float* att_dst   = (const float*)d_in[5];
  const float* bias      = (const float*)d_in[6];
  float* out = (float*)d_out;

  char* ws = (char*)d_ws;
  unsigned*       xpb     = (unsigned*)ws;        ws += (size_t)N_NODES * 64 * 4;  // 12.8 MB
  float*          a_src   = (float*)ws;           ws += (size_t)N_NODES * 4;
  float*          a_dst   = (float*)ws;           ws += (size_t)N_NODES * 4;
  unsigned short* wT      = (unsigned short*)ws;  ws += 144 * 256 * 2;             // 73.7 KB
  int*            gcursor = (int*)ws;             ws += ((NBKT + 127) / 128) * 128 * 4;
  unsigned*       coarse  = (unsigned*)ws;        ws += (size_t)NBKT * BKT_STRIDE * 4;  // 8.1 MB

  k0_init<<<18, 256, 0, stream>>>(v_mapping, att_src, att_dst, W_src, wT, gcursor);
  k1_fused<<<3 * NB_HIST, 256, 0, stream>>>(x, wT, xpb, a_src, a_dst, ei, gcursor, coarse);
  kc2_reduce<<<NBKT, 512, 0, stream>>>(gcursor, coarse, a_src, a_dst, xpb, bias, out);
}

// Round 20
// 126.948 us; speedup vs baseline: 1.0181x; 1.0181x over previous
//
#include <hip/hip_runtime.h>

#define N_NODES 50000
#define E_EDGES 1600000
#define HC 128
#define NEG_SLOPE 0.2f
#define SM_EPS 1e-16f
#define NBKT 782          // ceil(50000/64) coarse buckets (dst>>6)
#define BKT_STRIDE 2600   // slack per bucket (avg 2046, +12 sigma)
#define EPB1 3072         // edges per hist-role block
#define NB_GEMM 782
#define NB_HIST 521

typedef __attribute__((ext_vector_type(8))) short short8v;
typedef __attribute__((ext_vector_type(4))) float f32x4;

union U8 { uint4 u; short8v s; };

__device__ inline unsigned bf16pack(float a, float b) {
  unsigned ua = __float_as_uint(a), ub = __float_as_uint(b);
  ua = (ua + 0x7fffu + ((ua >> 16) & 1u)) >> 16;
  ub = (ub + 0x7fffu + ((ub >> 16) & 1u)) >> 16;
  return ua | (ub << 16);
}

// ---------------- K0: build wT[144][256] bf16 (W^T with wvec cols); init gcursor --
__global__ __launch_bounds__(256) void k0_init(
    const float* __restrict__ v_mapping,  // [64,256]
    const float* __restrict__ att_src,    // [64]
    const float* __restrict__ att_dst,    // [64]
    const float* __restrict__ W,          // [256,128]
    unsigned short* __restrict__ wT,      // [144,256] bf16
    int* __restrict__ gcursor) {
  const int tid = threadIdx.x, bid = blockIdx.x;
  if (bid < 4) {
    const int i = bid * 256 + tid;
    if (i < NBKT) gcursor[i] = i * BKT_STRIDE;
  }

  __shared__ float wv[2][256];
  {
    const int j = tid;
    float ns = 0.f, nd = 0.f;
    for (int f = 0; f < 64; ++f) {
      float a = att_src[f]; ns = fmaf(a, a, ns);
      float b = att_dst[f]; nd = fmaf(b, b, nd);
    }
    ns = fmaxf(sqrtf(ns), 1e-12f);
    nd = fmaxf(sqrtf(nd), 1e-12f);
    float s = 0.f, d = 0.f;
    for (int f = 0; f < 64; ++f) {
      float v = v_mapping[f * 256 + j];
      s = fmaf(v, att_src[f], s);
      d = fmaf(v, att_dst[f], d);
    }
    wv[0][j] = s / ns;
    wv[1][j] = d / nd;
  }
  __syncthreads();

#pragma unroll
  for (int r = 0; r < 8; ++r) {
    const int n = bid * 8 + r;
    const int k = tid;
    float v;
    if (n < 128) v = W[k * 128 + n];
    else if (n == 128) v = wv[0][k];
    else if (n == 129) v = wv[1][k];
    else v = 0.f;
    unsigned u = __float_as_uint(v);
    u = (u + 0x7fffu + ((u >> 16) & 1u)) >> 16;
    wT[n * 256 + k] = (unsigned short)u;
  }
}

// ---------------- K1F: role-fused — 3:2 interleave of GEMM (reg-A, 17KB LDS) and
// ---------------- bucket-scatter (rank from first hist pass) ----------------------
__global__ __launch_bounds__(256) void k1_fused(
    const float* __restrict__ x,            // [N,256]
    const unsigned short* __restrict__ wT,  // [144,256] bf16
    unsigned* __restrict__ xpb,             // [N,64] bf16x2 packed
    float* __restrict__ a_src, float* __restrict__ a_dst,
    const int* __restrict__ ei,
    int* __restrict__ gcursor, unsigned* __restrict__ coarse) {
  __shared__ char smem[17408];
  const int bid = blockIdx.x;
  const int tid = threadIdx.x;
  const int r5 = bid % 5, q5 = bid / 5;

  if (r5 >= 3) {
    // -------- bucket-scatter role: 3072 edges; rank = first-pass atomic return
    const int hid = q5 * 2 + (r5 - 3);
    if (hid >= NB_HIST) return;
    int* chist = (int*)smem;
    int* gbase = (int*)(smem + 3200);
    const int ebase = hid * EPB1;
    for (int b = tid; b < NBKT; b += 256) chist[b] = 0;
    __syncthreads();

    // pass A: histogram; atomic return IS the within-block rank
    int rnk[12];
#pragma unroll
    for (int i = 0; i < 12; ++i) {
      const int e = ebase + i * 256 + tid;
      rnk[i] = (e < E_EDGES) ? atomicAdd(&chist[ei[E_EDGES + e] >> 6], 1) : 0;
    }
    __syncthreads();

    // claim one global range per nonempty bucket
    for (int b = tid; b < NBKT; b += 256) {
      const int c = chist[b];
      if (c > 0) gbase[b] = atomicAdd(&gcursor[b], c);
    }
    __syncthreads();

    // pass B: pure scatter, no cursor atomics
#pragma unroll
    for (int i = 0; i < 12; ++i) {
      const int e = ebase + i * 256 + tid;
      if (e < E_EDGES) {
        const int s = ei[e];
        const int d = ei[E_EDGES + e];
        const int b = d >> 6;
        const int pos = gbase[b] + rnk[i];
        if (pos < (b + 1) * BKT_STRIDE)
          coarse[pos] = (unsigned)s | ((unsigned)(d & 63) << 16);
      }
    }
    return;
  }

  // -------- GEMM role: A-frags from global into registers, 2-chunk epilogue
  const int gid = q5 * 3 + r5;
  if (gid >= NB_GEMM) return;
  const int w = tid >> 6, lane = tid & 63;
  const int rowbase = gid * 64;
  const int m = lane & 15, kq = lane >> 4;

  const int arow_idx = rowbase + w * 16 + m;
  const int arow_c = arow_idx < N_NODES ? arow_idx : N_NODES - 1;
  const float4* xr = (const float4*)(x + (size_t)arow_c * 256);
  short8v af[8];
#pragma unroll
  for (int ks = 0; ks < 8; ++ks) {
    const float4 p0 = xr[kq * 2 + ks * 8];
    const float4 p1 = xr[kq * 2 + ks * 8 + 1];
    U8 t;
    t.u = make_uint4(bf16pack(p0.x, p0.y), bf16pack(p0.z, p0.w),
                     bf16pack(p1.x, p1.y), bf16pack(p1.z, p1.w));
    af[ks] = t.s;
  }

  f32x4 acc[9];
#pragma unroll
  for (int t = 0; t < 9; ++t) acc[t] = (f32x4){0.f, 0.f, 0.f, 0.f};

#pragma unroll
  for (int ks = 0; ks < 8; ++ks) {
#pragma unroll
    for (int ct = 0; ct < 9; ++ct) {
      const short8v bf = *(const short8v*)(wT + (ct * 16 + m) * 256 + ks * 32 + kq * 8);
      acc[ct] = __builtin_amdgcn_mfma_f32_16x16x32_bf16(af[ks], bf, acc[ct], 0, 0, 0);
    }
  }

  if (m < 2) {
    float* ap = m ? a_dst : a_src;
#pragma unroll
    for (int i = 0; i < 4; ++i) {
      const int rg = rowbase + w * 16 + kq * 4 + i;
      if (rg < N_NODES) ap[rg] = acc[8][i];
    }
  }

  float* cs = (float*)smem + w * 1088;
  const int prow = lane & 15, q = lane >> 4;
  const int growp = rowbase + w * 16 + prow;
#pragma unroll
  for (int half = 0; half < 2; ++half) {
#pragma unroll
    for (int ct = 0; ct < 4; ++ct)
#pragma unroll
      for (int i = 0; i < 4; ++i)
        cs[(kq * 4 + i) * 68 + ct * 16 + m] = acc[half * 4 + ct][i];
    __syncthreads();
    unsigned uu[8];
#pragma unroll
    for (int u2 = 0; u2 < 8; ++u2) {
      const float2 f2 = *(const float2*)&cs[prow * 68 + q * 16 + u2 * 2];
      uu[u2] = bf16pack(f2.x, f2.y);
    }
    if (growp < N_NODES) {
      uint4* d4 = (uint4*)&xpb[(size_t)growp * 64 + half * 32 + q * 8];
      d4[0] = make_uint4(uu[0], uu[1], uu[2], uu[3]);
      d4[1] = make_uint4(uu[4], uu[5], uu[6], uu[7]);
    }
    __syncthreads();
  }
}

// ---------------- KC2: ev + per-bucket LDS counting-sort + gather-reduce, 512 thr -
__global__ __launch_bounds__(512) void kc2_reduce(
    const int* __restrict__ gcursor, const unsigned* __restrict__ coarse,
    const float* __restrict__ a_src, const float* __restrict__ a_dst,
    const unsigned* __restrict__ xpb,   // [N,64] bf16x2
    const float* __restrict__ bias,     // [128]
    float* __restrict__ out) {
  __shared__ unsigned sorted[BKT_STRIDE];  // {src:16 | ev_bf16:16}
  __shared__ int hist[64], cur[64];
  __shared__ int base[65];
  __shared__ float adl[64];
  const int b = blockIdx.x;
  const int tid = threadIdx.x;
  const int cstart = b * BKT_STRIDE;
  const int cnt = min(gcursor[b] - cstart, BKT_STRIDE);

  if (tid < 64) {
    hist[tid] = 0; cur[tid] = 0;
    const int dg = (b << 6) | tid;
    adl[tid] = (dg < N_NODES) ? a_dst[dg] : 0.f;
  }
  __syncthreads();

  for (int j = tid; j < cnt; j += 512)
    atomicAdd(&hist[(coarse[cstart + j] >> 16) & 63], 1);
  __syncthreads();

  if (tid < 64) {
    const int h = hist[tid];
    int inc = h;
#pragma unroll
    for (int off = 1; off < 64; off <<= 1) {
      int t = __shfl_up(inc, off);
      if (tid >= off) inc += t;
    }
    base[tid] = inc - h;
    if (tid == 63) base[64] = inc;
  }
  __syncthreads();

  for (int j = tid; j < cnt; j += 512) {
    const unsigned e2 = coarse[cstart + j];
    const int src = e2 & 0xffffu;
    const int dloc = (e2 >> 16) & 63;
    float a = a_src[src] + adl[dloc];
    a = a > 0.f ? a : NEG_SLOPE * a;
    unsigned uev = __float_as_uint(__expf(a));
    uev = (uev + 0x7fffu + ((uev >> 16) & 1u)) >> 16;
    const int p = base[dloc] + atomicAdd(&cur[dloc], 1);
    sorted[p] = (unsigned)src | (uev << 16);
  }
  __syncthreads();

  const int g = tid >> 4, gl = tid & 15;
  const uint4* xp4 = (const uint4*)xpb;
  const float4* br = (const float4*)bias;
  const float4 b0 = br[2 * gl], b1 = br[2 * gl + 1];

  for (int dl = g; dl < 64; dl += 32) {
    const int dst = (b << 6) | dl;
    if (dst >= N_NODES) break;
    const int s0 = base[dl];
    const int cntd = base[dl + 1] - s0;

    float acc[8];
#pragma unroll
    for (int i = 0; i < 8; ++i) acc[i] = 0.f;
    float den = 0.f;

    int j = 0;
    for (; j + 4 <= cntd; j += 4) {
      unsigned u[4];
      float ev[4];
      uint4 v[4];
#pragma unroll
      for (int t = 0; t < 4; ++t) {
        u[t] = sorted[s0 + j + t];
        ev[t] = __uint_as_float(u[t] & 0xffff0000u);
        v[t] = xp4[(size_t)(u[t] & 0xffffu) * 16 + gl];
      }
#pragma unroll
      for (int t = 0; t < 4; ++t) {
        den += ev[t];
        acc[0] = fmaf(ev[t], __uint_as_float(v[t].x << 16), acc[0]);
        acc[1] = fmaf(ev[t], __uint_as_float(v[t].x & 0xffff0000u), acc[1]);
        acc[2] = fmaf(ev[t], __uint_as_float(v[t].y << 16), acc[2]);
        acc[3] = fmaf(ev[t], __uint_as_float(v[t].y & 0xffff0000u), acc[3]);
        acc[4] = fmaf(ev[t], __uint_as_float(v[t].z << 16), acc[4]);
        acc[5] = fmaf(ev[t], __uint_as_float(v[t].z & 0xffff0000u), acc[5]);
        acc[6] = fmaf(ev[t], __uint_as_float(v[t].w << 16), acc[6]);
        acc[7] = fmaf(ev[t], __uint_as_float(v[t].w & 0xffff0000u), acc[7]);
      }
    }
    for (; j < cntd; ++j) {
      const unsigned u = sorted[s0 + j];
      const float ev = __uint_as_float(u & 0xffff0000u);
      const uint4 v = xp4[(size_t)(u & 0xffffu) * 16 + gl];
      den += ev;
      acc[0] = fmaf(ev, __uint_as_float(v.x << 16), acc[0]);
      acc[1] = fmaf(ev, __uint_as_float(v.x & 0xffff0000u), acc[1]);
      acc[2] = fmaf(ev, __uint_as_float(v.y << 16), acc[2]);
      acc[3] = fmaf(ev, __uint_as_float(v.y & 0xffff0000u), acc[3]);
      acc[4] = fmaf(ev, __uint_as_float(v.z << 16), acc[4]);
      acc[5] = fmaf(ev, __uint_as_float(v.z & 0xffff0000u), acc[5]);
      acc[6] = fmaf(ev, __uint_as_float(v.w << 16), acc[6]);
      acc[7] = fmaf(ev, __uint_as_float(v.w & 0xffff0000u), acc[7]);
    }

    const float inv = 1.f / (den + SM_EPS);
    const uint4 ur = xp4[(size_t)dst * 16 + gl];
    float4 o0, o1;
    o0.x = __uint_as_float(ur.x << 16)         + b0.x + acc[0] * inv;
    o0.y = __uint_as_float(ur.x & 0xffff0000u) + b0.y + acc[1] * inv;
    o0.z = __uint_as_float(ur.y << 16)         + b0.z + acc[2] * inv;
    o0.w = __uint_as_float(ur.y & 0xffff0000u) + b0.w + acc[3] * inv;
    o1.x = __uint_as_float(ur.z << 16)         + b1.x + acc[4] * inv;
    o1.y = __uint_as_float(ur.z & 0xffff0000u) + b1.y + acc[5] * inv;
    o1.z = __uint_as_float(ur.w << 16)         + b1.z + acc[6] * inv;
    o1.w = __uint_as_float(ur.w & 0xffff0000u) + b1.w + acc[7] * inv;
    float4* orow = (float4*)(out + (size_t)dst * HC);
    orow[2 * gl] = o0;
    orow[2 * gl + 1] = o1;
  }
}

extern "C" void kernel_launch(void* const* d_in, const int* in_sizes, int n_in,
                              void* d_out, int out_size, void* d_ws, size_t ws_size,
                              hipStream_t stream) {
  const float* x         = (const float*)d_in[0];
  const int*   ei        = (const int*)d_in[1];
  const float* v_mapping = (const float*)d_in[2];
  const float* W_src     = (const float*)d_in[3];
  const float* att_src   = (const float*)d_in[4];
  const float* att_dst   = (const float*)d_in[5];
  const float* bias      = (const float*)d_in[6];
  float* out = (float*)d_out;

  char* ws = (char*)d_ws;
  unsigned*       xpb     = (unsigned*)ws;        ws += (size_t)N_NODES * 64 * 4;  // 12.8 MB
  float*          a_src   = (float*)ws;           ws += (size_t)N_NODES * 4;
  float*          a_dst   = (float*)ws;           ws += (size_t)N_NODES * 4;
  unsigned short* wT      = (unsigned short*)ws;  ws += 144 * 256 * 2;             // 73.7 KB
  int*            gcursor = (int*)ws;             ws += ((NBKT + 127) / 128) * 128 * 4;
  unsigned*       coarse  = (unsigned*)ws;        ws += (size_t)NBKT * BKT_STRIDE * 4;  // 8.1 MB

  k0_init<<<18, 256, 0, stream>>>(v_mapping, att_src, att_dst, W_src, wT, gcursor);
  k1_fused<<<1305, 256, 0, stream>>>(x, wT, xpb, a_src, a_dst, ei, gcursor, coarse);
  kc2_reduce<<<NBKT, 512, 0, stream>>>(gcursor, coarse, a_src, a_dst, xpb, bias, out);
}